// Round 2
// baseline (325.893 us; speedup 1.0000x reference)
//
#include <hip/hip_runtime.h>

// Problem constants (from reference)
static constexpr int kB = 2, kS = 2048, kD = 1024, kFF = 4096;
static constexpr int kM = kB * kS;  // 4096 token rows

typedef __attribute__((ext_vector_type(8))) short short8;
typedef __attribute__((ext_vector_type(4))) float f32x4;

__device__ __forceinline__ unsigned short f2bf(float f) {
  union { float f; unsigned int u; } c; c.f = f;
  unsigned int u = c.u;
  unsigned int r = u + 0x7FFFu + ((u >> 16) & 1u);  // RNE
  return (unsigned short)(r >> 16);
}

__device__ __forceinline__ void gload_lds16(const void* g, void* l) {
  __builtin_amdgcn_global_load_lds(
      (const __attribute__((address_space(1))) void*)g,
      (__attribute__((address_space(3))) void*)l, 16, 0, 0);
}

// ---------------- cast fp32 -> bf16 (vectorized) ----------------
__global__ __launch_bounds__(256) void cast_bf16_kernel(
    const float* __restrict__ in, unsigned short* __restrict__ out, int n) {
  int i = (blockIdx.x * 256 + threadIdx.x) * 4;
  if (i >= n) return;
  float4 v = *(const float4*)(in + i);
  ushort4 o;
  o.x = f2bf(v.x); o.y = f2bf(v.y); o.z = f2bf(v.z); o.w = f2bf(v.w);
  *(ushort4*)(out + i) = o;
}

// ------------- cast + transpose: W[K][N] fp32 -> Wt[N][K] bf16 (× scale) -------------
__global__ __launch_bounds__(1024) void cast_transpose_kernel(
    const float* __restrict__ W, unsigned short* __restrict__ Wt,
    int K, int N, float scale) {
  __shared__ float tile[32][33];
  int nb = blockIdx.x * 32, kb = blockIdx.y * 32;
  int tx = threadIdx.x, ty = threadIdx.y;
  tile[ty][tx] = W[(size_t)(kb + ty) * N + (nb + tx)];
  __syncthreads();
  Wt[(size_t)(nb + ty) * K + (kb + tx)] = f2bf(tile[tx][ty] * scale);
}

// --------- bc[n] = 2048 * sum_f bv[f]*Wo[f][n] + bo[n]  (D=1024) ---------
__global__ __launch_bounds__(256) void bias_combine_kernel(
    const float* __restrict__ bv, const float* __restrict__ Wo,
    const float* __restrict__ bo, float* __restrict__ bc) {
  const int n = blockIdx.x * 256 + threadIdx.x;  // grid 4 x 256 = 1024
  float acc = 0.0f;
#pragma unroll 4
  for (int f = 0; f < 1024; ++f) acc = fmaf(bv[f], Wo[(size_t)f * 1024 + n], acc);
  bc[n] = 2048.0f * acc + bo[n];
}

// ---------------- GEMM: C[M,N] = A[M,K] @ Bt[N,K]^T + bias (opt relu) ----------------
// 128x128 tile, BK=64, 4 waves (2x2), each wave 64x64 via 4x4 of 16x16x32 MFMA.
// Double-buffered LDS with stage-ahead prefetch (T3-minimum 2-phase) + bijective
// XCD swizzle on a 1D grid (T1).
template <int OUT_BF16, int RELU>
__global__ __launch_bounds__(256) void gemm_bt(
    const unsigned short* __restrict__ A, const unsigned short* __restrict__ Bt,
    const float* __restrict__ bias, void* __restrict__ Cout,
    int M, int N, int K, int nXtiles) {
  __shared__ __align__(16) unsigned short sA[2][128 * 64];
  __shared__ __align__(16) unsigned short sB[2][128 * 64];
  const int tid = threadIdx.x;
  const int wave = tid >> 6, lane = tid & 63;
  const int wr = wave >> 1, wc = wave & 1;

  // bijective XCD-aware swizzle (all grids are %8 == 0 here, but use m204 form)
  const int nwg = gridDim.x;
  const int q = nwg >> 3, r = nwg & 7;
  const int xcd = blockIdx.x & 7, pos = blockIdx.x >> 3;
  const int swz = (xcd < r) ? (xcd * (q + 1) + pos) : (r * (q + 1) + (xcd - r) * q + pos);
  const int m0 = (swz / nXtiles) * 128, n0 = (swz % nXtiles) * 128;

  const int srow = lane >> 3, scol = (lane & 7) * 8;

  f32x4 acc[4][4] = {};

  auto stage = [&](int buf, int k0) {
#pragma unroll
    for (int i = 0; i < 4; ++i) {
      const int chunk = i * 4 + wave;  // 16 chunks of 8 rows each
      const int rr = chunk * 8 + srow;
      gload_lds16(A + (size_t)(m0 + rr) * K + (k0 + scol), &sA[buf][chunk * 512]);
      gload_lds16(Bt + (size_t)(n0 + rr) * K + (k0 + scol), &sB[buf][chunk * 512]);
    }
  };

  stage(0, 0);
  int cur = 0;
  for (int k0 = 0; k0 < K; k0 += 64) {
    __syncthreads();  // implicit vmcnt(0): stage(cur) complete, prev reads done
    if (k0 + 64 < K) stage(cur ^ 1, k0 + 64);  // prefetch next tile (in flight
                                               // across the compute below)
#pragma unroll
    for (int kk = 0; kk < 64; kk += 32) {
      const int kcol = kk + (lane >> 4) * 8;
      short8 af[4], bfr[4];
#pragma unroll
      for (int m = 0; m < 4; ++m)
        af[m] = *(const short8*)&sA[cur][(wr * 64 + m * 16 + (lane & 15)) * 64 + kcol];
#pragma unroll
      for (int n = 0; n < 4; ++n)
        bfr[n] = *(const short8*)&sB[cur][(wc * 64 + n * 16 + (lane & 15)) * 64 + kcol];
#pragma unroll
      for (int m = 0; m < 4; ++m)
#pragma unroll
        for (int n = 0; n < 4; ++n)
          acc[m][n] = __builtin_amdgcn_mfma_f32_16x16x32_bf16(af[m], bfr[n], acc[m][n], 0, 0, 0);
    }
    cur ^= 1;
  }

  const int cl = lane & 15, rg = lane >> 4;
#pragma unroll
  for (int n = 0; n < 4; ++n) {
    const int col = n0 + wc * 64 + n * 16 + cl;
    const float bias_v = bias ? bias[col] : 0.0f;
#pragma unroll
    for (int m = 0; m < 4; ++m) {
      const int rbase = m0 + wr * 64 + m * 16 + rg * 4;
#pragma unroll
      for (int j = 0; j < 4; ++j) {
        float v = acc[m][n][j] + bias_v;
        if (RELU) v = fmaxf(v, 0.0f);
        if (OUT_BF16)
          ((unsigned short*)Cout)[(size_t)(rbase + j) * N + col] = f2bf(v);
        else
          ((float*)Cout)[(size_t)(rbase + j) * N + col] = v;
      }
    }
  }
}

// -------- fused residual + LayerNorm over D=1024: H = LN(X + Y) * g + b --------
__global__ __launch_bounds__(256) void ln_res_kernel(
    const float* __restrict__ X, const float* Y,
    const float* __restrict__ gg, const float* __restrict__ bb,
    float* Hf, unsigned short* Hb) {
  const int row = blockIdx.x, t = threadIdx.x;
  const size_t base = (size_t)row * 1024 + t * 4;
  float4 xv = *(const float4*)(X + base);
  float4 yv = *(const float4*)(Y + base);
  float a0 = xv.x + yv.x, a1 = xv.y + yv.y, a2 = xv.z + yv.z, a3 = xv.w + yv.w;
  float s = a0 + a1 + a2 + a3;
  float ss = a0 * a0 + a1 * a1 + a2 * a2 + a3 * a3;
#pragma unroll
  for (int off = 32; off > 0; off >>= 1) {
    s += __shfl_down(s, off);
    ss += __shfl_down(ss, off);
  }
  __shared__ float rs[4], rss[4];
  __shared__ float smean, srstd;
  const int wave = t >> 6, lane = t & 63;
  if (lane == 0) { rs[wave] = s; rss[wave] = ss; }
  __syncthreads();
  if (t == 0) {
    float S1 = rs[0] + rs[1] + rs[2] + rs[3];
    float S2 = rss[0] + rss[1] + rss[2] + rss[3];
    float mean = S1 * (1.0f / 1024.0f);
    float var = S2 * (1.0f / 1024.0f) - mean * mean;
    smean = mean;
    srstd = rsqrtf(var + 1e-5f);
  }
  __syncthreads();
  const float mean = smean, rstd = srstd;
  float4 gv = *(const float4*)(gg + t * 4);
  float4 bv = *(const float4*)(bb + t * 4);
  float o0 = (a0 - mean) * rstd * gv.x + bv.x;
  float o1 = (a1 - mean) * rstd * gv.y + bv.y;
  float o2 = (a2 - mean) * rstd * gv.z + bv.z;
  float o3 = (a3 - mean) * rstd * gv.w + bv.w;
  float4 ov; ov.x = o0; ov.y = o1; ov.z = o2; ov.w = o3;
  *(float4*)(Hf + base) = ov;
  if (Hb) {
    ushort4 hb;
    hb.x = f2bf(o0); hb.y = f2bf(o1); hb.z = f2bf(o2); hb.w = f2bf(o3);
    *(ushort4*)(Hb + base) = hb;
  }
}

// ---------------------------------------------------------------------------
// Attention is algebraically dead: softmax over q sums to 1 per (b,h,k) column;
// summed over k -> s_bh == S == 2048 exactly. So
//   att = z @ (2048*Wv@Wo) + (2048*bv@Wo + bo)      [q, k, mask unused]
//   out = LN(h1 + relu(h1@W1+b1)@W2 + b2),  h1 = LN(z + att)
// ---------------------------------------------------------------------------
extern "C" void kernel_launch(void* const* d_in, const int* in_sizes, int n_in,
                              void* d_out, int out_size, void* d_ws, size_t ws_size,
                              hipStream_t stream) {
  const float* z  = (const float*)d_in[2];
  const float* Wv = (const float*)d_in[8];
  const float* bv = (const float*)d_in[9];
  const float* Wo = (const float*)d_in[10];
  const float* bo = (const float*)d_in[11];
  const float* W1 = (const float*)d_in[12];
  const float* b1 = (const float*)d_in[13];
  const float* W2 = (const float*)d_in[14];
  const float* b2 = (const float*)d_in[15];
  const float* lng = (const float*)d_in[16];
  const float* lnb = (const float*)d_in[17];
  float* out = (float*)d_out;

  char* ws = (char*)d_ws;
  // layout (bytes):
  //   [0,   8M)  zbf (bf16 z)            -- dead after att GEMM
  //   [0,  16M)  ff  (fp32)              -- written by last GEMM (reuses zbf)
  //   [8M, 16M)  h1bf (bf16)
  //   [16M,24M)  weight region:
  //        phase 1: WoT*2048 @16M (2MB), WvBf @18M (2MB), WcT @20M (2MB), bc @22M (4KB)
  //        phase 2: W1T (8MB) then W2T (8MB) @16M
  //   [24M,40M)  att / h1f (fp32)
  //   [40M,72M)  a1 (bf16 relu output)
  unsigned short* zbf  = (unsigned short*)(ws + 0);
  float*          ff   = (float*)(ws + 0);
  unsigned short* h1bf = (unsigned short*)(ws + 8388608);
  unsigned short* WoT  = (unsigned short*)(ws + 16777216);
  unsigned short* WvBf = (unsigned short*)(ws + 18874368);
  unsigned short* WcT  = (unsigned short*)(ws + 20971520);
  float*          bc   = (float*)(ws + 23068672);
  unsigned short* wT   = (unsigned short*)(ws + 16777216);  // W1T / W2T
  float*          att  = (float*)(ws + 25165824);
  unsigned short* a1   = (unsigned short*)(ws + 41943040);

  const int nZ = kM * kD;  // 4194304

  // --- fold attention: WcT[n][d] = sum_f (2048*Wo[f][n]) * Wv[d][f] ---
  cast_transpose_kernel<<<dim3(kD / 32, kD / 32), dim3(32, 32), 0, stream>>>(
      Wo, WoT, kD, kD, (float)kS);                 // WoT[n][f] = 2048*Wo[f][n]
  cast_bf16_kernel<<<dim3(kD * kD / 1024), dim3(256), 0, stream>>>(Wv, WvBf, kD * kD);
  gemm_bt<1, 0><<<dim3(64), dim3(256), 0, stream>>>(
      WoT, WvBf, nullptr, WcT, kD, kD, kD, kD / 128);
  bias_combine_kernel<<<dim3(4), dim3(256), 0, stream>>>(bv, Wo, bo, bc);

  // z -> bf16
  cast_bf16_kernel<<<dim3(nZ / 1024), dim3(256), 0, stream>>>(z, zbf, nZ);

  // att = z @ Wc + bc   (fp32 out)
  gemm_bt<0, 0><<<dim3(256), dim3(256), 0, stream>>>(
      zbf, WcT, bc, att, kM, kD, kD, kD / 128);

  // h1 = LN(z + att): fp32 in place into att, bf16 into h1bf
  ln_res_kernel<<<dim3(kM), dim3(256), 0, stream>>>(z, att, lng, lnb, att, h1bf);

  // W1^T bf16 [FF][D]
  cast_transpose_kernel<<<dim3(kFF / 32, kD / 32), dim3(32, 32), 0, stream>>>(
      W1, wT, kD, kFF, 1.0f);
  // a1 = relu(h1 @ W1 + b1)   (bf16 out)
  gemm_bt<1, 1><<<dim3(1024), dim3(256), 0, stream>>>(
      h1bf, wT, b1, a1, kM, kFF, kD, kFF / 128);

  // W2^T bf16 [D][FF]
  cast_transpose_kernel<<<dim3(kD / 32, kFF / 32), dim3(32, 32), 0, stream>>>(
      W2, wT, kFF, kD, 1.0f);
  // ff = a1 @ W2 + b2   (fp32 out)
  gemm_bt<0, 0><<<dim3(256), dim3(256), 0, stream>>>(
      a1, wT, b2, ff, kM, kD, kFF, kD / 128);

  // out = LN(h1 + ff)
  ln_res_kernel<<<dim3(kM), dim3(256), 0, stream>>>(att, ff, lng, lnb, out, nullptr);
}

// Round 3
// 265.738 us; speedup vs baseline: 1.2264x; 1.2264x over previous
//
#include <hip/hip_runtime.h>

// Problem constants (from reference)
static constexpr int kB = 2, kS = 2048, kD = 1024, kFF = 4096;
static constexpr int kM = kB * kS;  // 4096 token rows
static constexpr size_t MB = 1u << 20;

typedef __attribute__((ext_vector_type(8))) short short8;
typedef __attribute__((ext_vector_type(4))) float f32x4;

__device__ __forceinline__ unsigned short f2bf(float f) {
  union { float f; unsigned int u; } c; c.f = f;
  unsigned int u = c.u;
  unsigned int r = u + 0x7FFFu + ((u >> 16) & 1u);  // RNE
  return (unsigned short)(r >> 16);
}

__device__ __forceinline__ void gload_lds16(const void* g, void* l) {
  __builtin_amdgcn_global_load_lds(
      (const __attribute__((address_space(1))) void*)g,
      (__attribute__((address_space(3))) void*)l, 16, 0, 0);
}

// ---------------- cast fp32 -> bf16 (vectorized) ----------------
__global__ __launch_bounds__(256) void cast_bf16_kernel(
    const float* __restrict__ in, unsigned short* __restrict__ out, int n) {
  int i = (blockIdx.x * 256 + threadIdx.x) * 4;
  if (i >= n) return;
  float4 v = *(const float4*)(in + i);
  ushort4 o;
  o.x = f2bf(v.x); o.y = f2bf(v.y); o.z = f2bf(v.z); o.w = f2bf(v.w);
  *(ushort4*)(out + i) = o;
}

// ------------- cast + transpose: W[K][N] fp32 -> Wt[N][K] bf16 (× scale) -------------
__global__ __launch_bounds__(1024) void cast_transpose_kernel(
    const float* __restrict__ W, unsigned short* __restrict__ Wt,
    int K, int N, float scale) {
  __shared__ float tile[32][33];
  int nb = blockIdx.x * 32, kb = blockIdx.y * 32;
  int tx = threadIdx.x, ty = threadIdx.y;
  tile[ty][tx] = W[(size_t)(kb + ty) * N + (nb + tx)];
  __syncthreads();
  Wt[(size_t)(nb + ty) * K + (kb + tx)] = f2bf(tile[tx][ty] * scale);
}

// --------- bc[n] = 2048 * sum_f bv[f]*Wo[f][n] + bo[n]  (D=1024) ---------
__global__ __launch_bounds__(256) void bias_combine_kernel(
    const float* __restrict__ bv, const float* __restrict__ Wo,
    const float* __restrict__ bo, float* __restrict__ bc) {
  const int n = blockIdx.x * 256 + threadIdx.x;  // grid 4 x 256 = 1024
  float acc = 0.0f;
#pragma unroll 4
  for (int f = 0; f < 1024; ++f) acc = fmaf(bv[f], Wo[(size_t)f * 1024 + n], acc);
  bc[n] = 2048.0f * acc + bo[n];
}

// -------- combine 4 fp32 split-K partials of Wc, add identity, cast bf16 --------
// WcT[m][n], identity on m==n. MN = 1024*1024.
__global__ __launch_bounds__(256) void combine_wc_kernel(
    const float* __restrict__ P, unsigned short* __restrict__ Wt) {
  const int i = (blockIdx.x * 256 + threadIdx.x) * 4;  // grid 1024
  const int MN = 1024 * 1024;
  float4 s0 = *(const float4*)(P + i);
  float4 s1 = *(const float4*)(P + MN + i);
  float4 s2 = *(const float4*)(P + 2 * MN + i);
  float4 s3 = *(const float4*)(P + 3 * MN + i);
  const int row = i >> 10, col = i & 1023;
  float v0 = s0.x + s1.x + s2.x + s3.x + (row == col + 0 ? 1.0f : 0.0f);
  float v1 = s0.y + s1.y + s2.y + s3.y + (row == col + 1 ? 1.0f : 0.0f);
  float v2 = s0.z + s1.z + s2.z + s3.z + (row == col + 2 ? 1.0f : 0.0f);
  float v3 = s0.w + s1.w + s2.w + s3.w + (row == col + 3 ? 1.0f : 0.0f);
  ushort4 o; o.x = f2bf(v0); o.y = f2bf(v1); o.z = f2bf(v2); o.w = f2bf(v3);
  *(ushort4*)(Wt + i) = o;
}

// ---------------- GEMM: C[M,N] = A[M,K] @ Bt[N,K]^T (+bias, opt relu, split-K) ----
// 128x128 tile, BK=64, 4 waves (2x2). Single 32KB LDS buffer (occupancy!),
// T2 XOR-swizzle via pre-swizzled global source + swizzled ds_read (rule 21),
// T1 bijective XCD swizzle. Split-K: grid = nSplits*nTilesPerSplit blocks;
// split s covers K rows [s*kSplitLen, (s+1)*kSplitLen), writes Cout + s*cSplitStride.
// bias applied only on split 0 (pass bias=nullptr to skip).
template <int OUT_BF16, int RELU>
__global__ __launch_bounds__(256) void gemm_bt(
    const unsigned short* __restrict__ A, const unsigned short* __restrict__ Bt,
    const float* __restrict__ bias, void* __restrict__ Cout,
    int M, int N, int K, int nXtiles, int nTilesPerSplit, int kSplitLen,
    size_t cSplitStride) {
  __shared__ __align__(16) unsigned short sA[128 * 64];
  __shared__ __align__(16) unsigned short sB[128 * 64];
  const int tid = threadIdx.x;
  const int wave = tid >> 6, lane = tid & 63;
  const int wr = wave >> 1, wc = wave & 1;

  // bijective XCD-aware swizzle (m204 form)
  const int nwg = gridDim.x;
  const int q = nwg >> 3, r = nwg & 7;
  const int xcd = blockIdx.x & 7, pos = blockIdx.x >> 3;
  const int swz = (xcd < r) ? (xcd * (q + 1) + pos) : (r * (q + 1) + (xcd - r) * q + pos);
  const int split = swz / nTilesPerSplit, rem = swz % nTilesPerSplit;
  const int m0 = (rem / nXtiles) * 128, n0 = (rem % nXtiles) * 128;
  const int kBeg = split * kSplitLen, kEnd = kBeg + kSplitLen;

  // staging geometry: 16 chunks of 8 rows x 64 cols (1KB) per matrix; wave w
  // stages chunks {w, w+4, w+8, w+12}. Lane l covers row (l>>3), 16B at
  // swizzled source col ((l&7)^(l>>3))*8 elements -> LDS stays linear.
  const int srow = lane >> 3;
  const int scol = ((lane & 7) ^ srow) * 8;  // pre-swizzled global col (elements)

  f32x4 acc[4][4] = {};

  for (int k0 = kBeg; k0 < kEnd; k0 += 64) {
#pragma unroll
    for (int i = 0; i < 4; ++i) {
      const int chunk = i * 4 + wave;
      const int rr = chunk * 8 + srow;
      gload_lds16(A + (size_t)(m0 + rr) * K + (k0 + scol), &sA[chunk * 512]);
      gload_lds16(Bt + (size_t)(n0 + rr) * K + (k0 + scol), &sB[chunk * 512]);
    }
    __syncthreads();  // drains staging (vmcnt 0)
#pragma unroll
    for (int kk = 0; kk < 64; kk += 32) {
      const int kcol = kk + (lane >> 4) * 8;
      const int kswz = (lane & 7) * 8;  // (row&7)*8 is lane-uniform across m/n frags
      short8 af[4], bfr[4];
#pragma unroll
      for (int m = 0; m < 4; ++m)
        af[m] = *(const short8*)&sA[(wr * 64 + m * 16 + (lane & 15)) * 64 + (kcol ^ kswz)];
#pragma unroll
      for (int n = 0; n < 4; ++n)
        bfr[n] = *(const short8*)&sB[(wc * 64 + n * 16 + (lane & 15)) * 64 + (kcol ^ kswz)];
#pragma unroll
      for (int m = 0; m < 4; ++m)
#pragma unroll
        for (int n = 0; n < 4; ++n)
          acc[m][n] = __builtin_amdgcn_mfma_f32_16x16x32_bf16(af[m], bfr[n], acc[m][n], 0, 0, 0);
    }
    __syncthreads();  // protect LDS reuse
  }

  const int cl = lane & 15, rg = lane >> 4;
  const float* bptr = (split == 0) ? bias : nullptr;
#pragma unroll
  for (int n = 0; n < 4; ++n) {
    const int col = n0 + wc * 64 + n * 16 + cl;
    const float bias_v = bptr ? bptr[col] : 0.0f;
#pragma unroll
    for (int m = 0; m < 4; ++m) {
      const int rbase = m0 + wr * 64 + m * 16 + rg * 4;
#pragma unroll
      for (int j = 0; j < 4; ++j) {
        float v = acc[m][n][j] + bias_v;
        if (RELU) v = fmaxf(v, 0.0f);
        if (OUT_BF16)
          ((unsigned short*)Cout)[(size_t)(rbase + j) * N + col] = f2bf(v);
        else
          ((float*)Cout)[split * cSplitStride + (size_t)(rbase + j) * N + col] = v;
      }
    }
  }
}

// -------- fused residual-sum + LayerNorm over D=1024: H = LN(X+Y[+Z]) * g + b --------
template <int NIN>
__global__ __launch_bounds__(256) void ln_res_kernel(
    const float* __restrict__ X, const float* __restrict__ Y, const float* __restrict__ Z,
    const float* __restrict__ gg, const float* __restrict__ bb,
    float* Hf, unsigned short* Hb) {
  const int row = blockIdx.x, t = threadIdx.x;
  const size_t base = (size_t)row * 1024 + t * 4;
  float4 xv = *(const float4*)(X + base);
  float4 yv = *(const float4*)(Y + base);
  float a0 = xv.x + yv.x, a1 = xv.y + yv.y, a2 = xv.z + yv.z, a3 = xv.w + yv.w;
  if (NIN == 3) {
    float4 zv = *(const float4*)(Z + base);
    a0 += zv.x; a1 += zv.y; a2 += zv.z; a3 += zv.w;
  }
  float s = a0 + a1 + a2 + a3;
  float ss = a0 * a0 + a1 * a1 + a2 * a2 + a3 * a3;
#pragma unroll
  for (int off = 32; off > 0; off >>= 1) {
    s += __shfl_down(s, off);
    ss += __shfl_down(ss, off);
  }
  __shared__ float rs[4], rss[4];
  __shared__ float smean, srstd;
  const int wave = t >> 6, lane = t & 63;
  if (lane == 0) { rs[wave] = s; rss[wave] = ss; }
  __syncthreads();
  if (t == 0) {
    float S1 = rs[0] + rs[1] + rs[2] + rs[3];
    float S2 = rss[0] + rss[1] + rss[2] + rss[3];
    float mean = S1 * (1.0f / 1024.0f);
    float var = S2 * (1.0f / 1024.0f) - mean * mean;
    smean = mean;
    srstd = rsqrtf(var + 1e-5f);
  }
  __syncthreads();
  const float mean = smean, rstd = srstd;
  float4 gv = *(const float4*)(gg + t * 4);
  float4 bv = *(const float4*)(bb + t * 4);
  float o0 = (a0 - mean) * rstd * gv.x + bv.x;
  float o1 = (a1 - mean) * rstd * gv.y + bv.y;
  float o2 = (a2 - mean) * rstd * gv.z + bv.z;
  float o3 = (a3 - mean) * rstd * gv.w + bv.w;
  float4 ov; ov.x = o0; ov.y = o1; ov.z = o2; ov.w = o3;
  *(float4*)(Hf + base) = ov;
  if (Hb) {
    ushort4 hb;
    hb.x = f2bf(o0); hb.y = f2bf(o1); hb.z = f2bf(o2); hb.w = f2bf(o3);
    *(ushort4*)(Hb + base) = hb;
  }
}

// ---------------------------------------------------------------------------
// Attention is algebraically dead: softmax over q sums to 1 per (b,h,k) column;
// summed over k -> s_bh == S == 2048 exactly. Folding the residual too:
//   h1  = LN( z @ (I + 2048*Wv@Wo) + (2048*bv@Wo + bo) )
//   out = LN( h1 + relu(h1@W1+b1)@W2 + b2 )
// q, k, mask, x, y, Wq, Wk are all unused.
// ---------------------------------------------------------------------------
extern "C" void kernel_launch(void* const* d_in, const int* in_sizes, int n_in,
                              void* d_out, int out_size, void* d_ws, size_t ws_size,
                              hipStream_t stream) {
  const float* z  = (const float*)d_in[2];
  const float* Wv = (const float*)d_in[8];
  const float* bv = (const float*)d_in[9];
  const float* Wo = (const float*)d_in[10];
  const float* bo = (const float*)d_in[11];
  const float* W1 = (const float*)d_in[12];
  const float* b1 = (const float*)d_in[13];
  const float* W2 = (const float*)d_in[14];
  const float* b2 = (const float*)d_in[15];
  const float* lng = (const float*)d_in[16];
  const float* lnb = (const float*)d_in[17];
  float* out = (float*)d_out;

  char* ws = (char*)d_ws;
  // layout (MB offsets), peak 112MB:
  //   zbf   @0..8    (bf16 z; dead after att GEMM)
  //   h1f   @8..24   (fp32)
  //   h1bf  @24..32  (bf16; dead after FF1)
  //   wT    @32..40  (W1T then W2T bf16)
  //   WoT   @40..42, WvBf @42..44, WcT @44..46, bc @46
  //   wcp   @48..64  (4 fp32 Wc partials; dead after combine)
  //   attP  @48..80  (2 fp32 partials; dead after LN1)
  //   a1    @80..112 (bf16 relu out)
  //   ffP   @48..80  (2 fp32 partials)
  unsigned short* zbf  = (unsigned short*)(ws + 0 * MB);
  float*          h1f  = (float*)(ws + 8 * MB);
  unsigned short* h1bf = (unsigned short*)(ws + 24 * MB);
  unsigned short* wT   = (unsigned short*)(ws + 32 * MB);
  unsigned short* WoT  = (unsigned short*)(ws + 40 * MB);
  unsigned short* WvBf = (unsigned short*)(ws + 42 * MB);
  unsigned short* WcT  = (unsigned short*)(ws + 44 * MB);
  float*          bc   = (float*)(ws + 46 * MB);
  float*          wcp  = (float*)(ws + 48 * MB);
  float*          attP = (float*)(ws + 48 * MB);
  unsigned short* a1   = (unsigned short*)(ws + 80 * MB);
  float*          ffP  = (float*)(ws + 48 * MB);

  const int nZ = kM * kD;  // 4194304

  // --- weight prep ---
  cast_transpose_kernel<<<dim3(kD / 32, kD / 32), dim3(32, 32), 0, stream>>>(
      Wo, WoT, kD, kD, (float)kS);                 // WoT[n][f] = 2048*Wo[f][n]
  cast_bf16_kernel<<<dim3(kD * kD / 1024), dim3(256), 0, stream>>>(Wv, WvBf, kD * kD);
  bias_combine_kernel<<<dim3(4), dim3(256), 0, stream>>>(bv, Wo, bo, bc);
  cast_bf16_kernel<<<dim3(nZ / 1024), dim3(256), 0, stream>>>(z, zbf, nZ);

  // WcT[m][n] = sum_f WoT[m][f]*WvBf[n][f], split-K x4 (grid 256), then
  // combine + identity + bf16.
  gemm_bt<0, 0><<<dim3(256), dim3(256), 0, stream>>>(
      WoT, WvBf, nullptr, wcp, kD, kD, kD, kD / 128, 64, 256, (size_t)kD * kD);
  combine_wc_kernel<<<dim3(1024), dim3(256), 0, stream>>>(wcp, WcT);

  // attP = z @ (I+Wc) + bc, split-K x2 (grid 512)
  gemm_bt<0, 0><<<dim3(512), dim3(256), 0, stream>>>(
      zbf, WcT, bc, attP, kM, kD, kD, kD / 128, 256, 512, (size_t)kM * kD);

  // h1 = LN(attP0 + attP1)
  ln_res_kernel<2><<<dim3(kM), dim3(256), 0, stream>>>(
      attP, attP + (size_t)kM * kD, nullptr, lng, lnb, h1f, h1bf);

  // FF1: a1 = relu(h1 @ W1 + b1), grid 1024, no split
  cast_transpose_kernel<<<dim3(kFF / 32, kD / 32), dim3(32, 32), 0, stream>>>(
      W1, wT, kD, kFF, 1.0f);
  gemm_bt<1, 1><<<dim3(1024), dim3(256), 0, stream>>>(
      h1bf, wT, b1, a1, kM, kFF, kD, kFF / 128, 1024, kD, 0);

  // FF2: ffP = a1 @ W2 + b2, split-K x2 (grid 512)
  cast_transpose_kernel<<<dim3(kD / 32, kFF / 32), dim3(32, 32), 0, stream>>>(
      W2, wT, kFF, kD, 1.0f);
  gemm_bt<0, 0><<<dim3(512), dim3(256), 0, stream>>>(
      a1, wT, b2, ffP, kM, kD, kFF, kD / 128, 256, kFF / 2, (size_t)kM * kD);

  // out = LN(h1 + ffP0 + ffP1)
  ln_res_kernel<3><<<dim3(kM), dim3(256), 0, stream>>>(
      h1f, ffP, ffP + (size_t)kM * kD, lng, lnb, out, nullptr);
}

// Round 4
// 190.401 us; speedup vs baseline: 1.7116x; 1.3957x over previous
//
#include <hip/hip_runtime.h>

// Problem constants (from reference)
static constexpr int kB = 2, kS = 2048, kD = 1024, kFF = 4096;
static constexpr int kM = kB * kS;  // 4096 token rows
static constexpr size_t MB = 1u << 20;

typedef __attribute__((ext_vector_type(8))) short short8;
typedef __attribute__((ext_vector_type(4))) float f32x4;

__device__ __forceinline__ unsigned short f2bf(float f) {
  union { float f; unsigned int u; } c; c.f = f;
  unsigned int u = c.u;
  unsigned int r = u + 0x7FFFu + ((u >> 16) & 1u);  // RNE
  return (unsigned short)(r >> 16);
}

__device__ __forceinline__ void gload_lds16(const void* g, void* l) {
  __builtin_amdgcn_global_load_lds(
      (const __attribute__((address_space(1))) void*)g,
      (__attribute__((address_space(3))) void*)l, 16, 0, 0);
}

// ---------------- cast fp32 -> bf16 (vectorized) ----------------
__global__ __launch_bounds__(256) void cast_bf16_kernel(
    const float* __restrict__ in, unsigned short* __restrict__ out, int n) {
  int i = (blockIdx.x * 256 + threadIdx.x) * 4;
  if (i >= n) return;
  float4 v = *(const float4*)(in + i);
  ushort4 o;
  o.x = f2bf(v.x); o.y = f2bf(v.y); o.z = f2bf(v.z); o.w = f2bf(v.w);
  *(ushort4*)(out + i) = o;
}

// ------------- cast + transpose: W[K][N] fp32 -> Wt[N][K] bf16 (× scale) -------------
__global__ __launch_bounds__(1024) void cast_transpose_kernel(
    const float* __restrict__ W, unsigned short* __restrict__ Wt,
    int K, int N, float scale) {
  __shared__ float tile[32][33];
  int nb = blockIdx.x * 32, kb = blockIdx.y * 32;
  int tx = threadIdx.x, ty = threadIdx.y;
  tile[ty][tx] = W[(size_t)(kb + ty) * N + (nb + tx)];
  __syncthreads();
  Wt[(size_t)(nb + ty) * K + (kb + tx)] = f2bf(tile[tx][ty] * scale);
}

// --------- parallel GEMV phase 1: partial[b][n] = sum_{f in block b} bv[f]*Wo[f][n] ---
// grid 128, block 256. Block b owns rows [8b, 8b+8); coalesced float4 reads.
__global__ __launch_bounds__(256) void bias_gemv_part_kernel(
    const float* __restrict__ bv, const float* __restrict__ Wo,
    float* __restrict__ partial) {
  const int b = blockIdx.x, t = threadIdx.x;
  const int c = t * 4;
  float4 acc = {0.f, 0.f, 0.f, 0.f};
#pragma unroll
  for (int r = 0; r < 8; ++r) {
    const int f = b * 8 + r;
    const float s = bv[f];
    float4 w = *(const float4*)(Wo + (size_t)f * 1024 + c);
    acc.x = fmaf(s, w.x, acc.x);
    acc.y = fmaf(s, w.y, acc.y);
    acc.z = fmaf(s, w.z, acc.z);
    acc.w = fmaf(s, w.w, acc.w);
  }
  *(float4*)(partial + (size_t)b * 1024 + c) = acc;
}

// --------- GEMV phase 2: bc[n] = 2048 * sum_b partial[b][n] + bo[n] ---------
// grid 4, block 256; coalesced (consecutive threads -> consecutive n).
__global__ __launch_bounds__(256) void bias_gemv_fin_kernel(
    const float* __restrict__ partial, const float* __restrict__ bo,
    float* __restrict__ bc) {
  const int n = blockIdx.x * 256 + threadIdx.x;
  float acc = 0.0f;
#pragma unroll 8
  for (int b = 0; b < 128; ++b) acc += partial[(size_t)b * 1024 + n];
  bc[n] = 2048.0f * acc + bo[n];
}

// -------- combine 4 fp32 split-K partials of Wc, add identity, cast bf16 --------
__global__ __launch_bounds__(256) void combine_wc_kernel(
    const float* __restrict__ P, unsigned short* __restrict__ Wt) {
  const int i = (blockIdx.x * 256 + threadIdx.x) * 4;  // grid 1024
  const int MN = 1024 * 1024;
  float4 s0 = *(const float4*)(P + i);
  float4 s1 = *(const float4*)(P + MN + i);
  float4 s2 = *(const float4*)(P + 2 * MN + i);
  float4 s3 = *(const float4*)(P + 3 * MN + i);
  const int row = i >> 10, col = i & 1023;
  float v0 = s0.x + s1.x + s2.x + s3.x + (row == col + 0 ? 1.0f : 0.0f);
  float v1 = s0.y + s1.y + s2.y + s3.y + (row == col + 1 ? 1.0f : 0.0f);
  float v2 = s0.z + s1.z + s2.z + s3.z + (row == col + 2 ? 1.0f : 0.0f);
  float v3 = s0.w + s1.w + s2.w + s3.w + (row == col + 3 ? 1.0f : 0.0f);
  ushort4 o; o.x = f2bf(v0); o.y = f2bf(v1); o.z = f2bf(v2); o.w = f2bf(v3);
  *(ushort4*)(Wt + i) = o;
}

// ---------------- GEMM: C[M,N] = A[M,K] @ Bt[N,K]^T (+bias, opt relu, split-K) ----
// 128x128 tile, BK=64, 4 waves (2x2). Single 32KB LDS buffer (occupancy),
// T2 XOR-swizzle via pre-swizzled global source + swizzled ds_read (rule 21),
// T1 bijective XCD swizzle. Split-K: grid = nSplits*nTilesPerSplit blocks.
template <int OUT_BF16, int RELU>
__global__ __launch_bounds__(256) void gemm_bt(
    const unsigned short* __restrict__ A, const unsigned short* __restrict__ Bt,
    const float* __restrict__ bias, void* __restrict__ Cout,
    int M, int N, int K, int nXtiles, int nTilesPerSplit, int kSplitLen,
    size_t cSplitStride) {
  __shared__ __align__(16) unsigned short sA[128 * 64];
  __shared__ __align__(16) unsigned short sB[128 * 64];
  const int tid = threadIdx.x;
  const int wave = tid >> 6, lane = tid & 63;
  const int wr = wave >> 1, wc = wave & 1;

  // bijective XCD-aware swizzle (m204 form)
  const int nwg = gridDim.x;
  const int q = nwg >> 3, r = nwg & 7;
  const int xcd = blockIdx.x & 7, pos = blockIdx.x >> 3;
  const int swz = (xcd < r) ? (xcd * (q + 1) + pos) : (r * (q + 1) + (xcd - r) * q + pos);
  const int split = swz / nTilesPerSplit, rem = swz % nTilesPerSplit;
  const int m0 = (rem / nXtiles) * 128, n0 = (rem % nXtiles) * 128;
  const int kBeg = split * kSplitLen, kEnd = kBeg + kSplitLen;

  const int srow = lane >> 3;
  const int scol = ((lane & 7) ^ srow) * 8;  // pre-swizzled global col (elements)

  f32x4 acc[4][4] = {};

  for (int k0 = kBeg; k0 < kEnd; k0 += 64) {
#pragma unroll
    for (int i = 0; i < 4; ++i) {
      const int chunk = i * 4 + wave;
      const int rr = chunk * 8 + srow;
      gload_lds16(A + (size_t)(m0 + rr) * K + (k0 + scol), &sA[chunk * 512]);
      gload_lds16(Bt + (size_t)(n0 + rr) * K + (k0 + scol), &sB[chunk * 512]);
    }
    __syncthreads();  // drains staging (vmcnt 0)
#pragma unroll
    for (int kk = 0; kk < 64; kk += 32) {
      const int kcol = kk + (lane >> 4) * 8;
      const int kswz = (lane & 7) * 8;
      short8 af[4], bfr[4];
#pragma unroll
      for (int m = 0; m < 4; ++m)
        af[m] = *(const short8*)&sA[(wr * 64 + m * 16 + (lane & 15)) * 64 + (kcol ^ kswz)];
#pragma unroll
      for (int n = 0; n < 4; ++n)
        bfr[n] = *(const short8*)&sB[(wc * 64 + n * 16 + (lane & 15)) * 64 + (kcol ^ kswz)];
#pragma unroll
      for (int m = 0; m < 4; ++m)
#pragma unroll
        for (int n = 0; n < 4; ++n)
          acc[m][n] = __builtin_amdgcn_mfma_f32_16x16x32_bf16(af[m], bfr[n], acc[m][n], 0, 0, 0);
    }
    __syncthreads();  // protect LDS reuse
  }

  const int cl = lane & 15, rg = lane >> 4;
  const float* bptr = (split == 0) ? bias : nullptr;
#pragma unroll
  for (int n = 0; n < 4; ++n) {
    const int col = n0 + wc * 64 + n * 16 + cl;
    const float bias_v = bptr ? bptr[col] : 0.0f;
#pragma unroll
    for (int m = 0; m < 4; ++m) {
      const int rbase = m0 + wr * 64 + m * 16 + rg * 4;
#pragma unroll
      for (int j = 0; j < 4; ++j) {
        float v = acc[m][n][j] + bias_v;
        if (RELU) v = fmaxf(v, 0.0f);
        if (OUT_BF16)
          ((unsigned short*)Cout)[(size_t)(rbase + j) * N + col] = f2bf(v);
        else
          ((float*)Cout)[split * cSplitStride + (size_t)(rbase + j) * N + col] = v;
      }
    }
  }
}

// -------- fused residual-sum + LayerNorm over D=1024: H = LN(X+Y[+Z]) * g + b --------
template <int NIN>
__global__ __launch_bounds__(256) void ln_res_kernel(
    const float* __restrict__ X, const float* __restrict__ Y, const float* __restrict__ Z,
    const float* __restrict__ gg, const float* __restrict__ bb,
    float* Hf, unsigned short* Hb) {
  const int row = blockIdx.x, t = threadIdx.x;
  const size_t base = (size_t)row * 1024 + t * 4;
  float4 xv = *(const float4*)(X + base);
  float4 yv = *(const float4*)(Y + base);
  float a0 = xv.x + yv.x, a1 = xv.y + yv.y, a2 = xv.z + yv.z, a3 = xv.w + yv.w;
  if (NIN == 3) {
    float4 zv = *(const float4*)(Z + base);
    a0 += zv.x; a1 += zv.y; a2 += zv.z; a3 += zv.w;
  }
  float s = a0 + a1 + a2 + a3;
  float ss = a0 * a0 + a1 * a1 + a2 * a2 + a3 * a3;
#pragma unroll
  for (int off = 32; off > 0; off >>= 1) {
    s += __shfl_down(s, off);
    ss += __shfl_down(ss, off);
  }
  __shared__ float rs[4], rss[4];
  __shared__ float smean, srstd;
  const int wave = t >> 6, lane = t & 63;
  if (lane == 0) { rs[wave] = s; rss[wave] = ss; }
  __syncthreads();
  if (t == 0) {
    float S1 = rs[0] + rs[1] + rs[2] + rs[3];
    float S2 = rss[0] + rss[1] + rss[2] + rss[3];
    float mean = S1 * (1.0f / 1024.0f);
    float var = S2 * (1.0f / 1024.0f) - mean * mean;
    smean = mean;
    srstd = rsqrtf(var + 1e-5f);
  }
  __syncthreads();
  const float mean = smean, rstd = srstd;
  float4 gv = *(const float4*)(gg + t * 4);
  float4 bv = *(const float4*)(bb + t * 4);
  float o0 = (a0 - mean) * rstd * gv.x + bv.x;
  float o1 = (a1 - mean) * rstd * gv.y + bv.y;
  float o2 = (a2 - mean) * rstd * gv.z + bv.z;
  float o3 = (a3 - mean) * rstd * gv.w + bv.w;
  float4 ov; ov.x = o0; ov.y = o1; ov.z = o2; ov.w = o3;
  *(float4*)(Hf + base) = ov;
  if (Hb) {
    ushort4 hb;
    hb.x = f2bf(o0); hb.y = f2bf(o1); hb.z = f2bf(o2); hb.w = f2bf(o3);
    *(ushort4*)(Hb + base) = hb;
  }
}

// ---------------------------------------------------------------------------
// Attention is algebraically dead: softmax over q sums to 1 per (b,h,k) column;
// summed over k -> s_bh == S == 2048 exactly. Folding the residual too:
//   h1  = LN( z @ (I + 2048*Wv@Wo) + (2048*bv@Wo + bo) )
//   out = LN( h1 + relu(h1@W1+b1)@W2 + b2 )
// q, k, mask, x, y, Wq, Wk are all unused.
// ---------------------------------------------------------------------------
extern "C" void kernel_launch(void* const* d_in, const int* in_sizes, int n_in,
                              void* d_out, int out_size, void* d_ws, size_t ws_size,
                              hipStream_t stream) {
  const float* z  = (const float*)d_in[2];
  const float* Wv = (const float*)d_in[8];
  const float* bv = (const float*)d_in[9];
  const float* Wo = (const float*)d_in[10];
  const float* bo = (const float*)d_in[11];
  const float* W1 = (const float*)d_in[12];
  const float* b1 = (const float*)d_in[13];
  const float* W2 = (const float*)d_in[14];
  const float* b2 = (const float*)d_in[15];
  const float* lng = (const float*)d_in[16];
  const float* lnb = (const float*)d_in[17];
  float* out = (float*)d_out;

  char* ws = (char*)d_ws;
  // layout (MB offsets), peak 112MB:
  //   zbf   @0..8    (bf16 z; dead after att GEMM)
  //   h1f   @8..24   (fp32)
  //   h1bf  @24..32  (bf16; dead after FF1)
  //   wT    @32..40  (W1T then W2T bf16)
  //   WoT   @40..42, WvBf @42..44, WcT @44..46, bc @46, bpart @46+4KB
  //   wcp   @48..64  (4 fp32 Wc partials; dead after combine)
  //   attP  @48..80  (2 fp32 partials; dead after LN1)
  //   a1    @80..112 (bf16 relu out)
  //   ffP   @48..80  (2 fp32 partials)
  unsigned short* zbf  = (unsigned short*)(ws + 0 * MB);
  float*          h1f  = (float*)(ws + 8 * MB);
  unsigned short* h1bf = (unsigned short*)(ws + 24 * MB);
  unsigned short* wT   = (unsigned short*)(ws + 32 * MB);
  unsigned short* WoT  = (unsigned short*)(ws + 40 * MB);
  unsigned short* WvBf = (unsigned short*)(ws + 42 * MB);
  unsigned short* WcT  = (unsigned short*)(ws + 44 * MB);
  float*          bc   = (float*)(ws + 46 * MB);
  float*          bprt = (float*)(ws + 46 * MB + 65536);
  float*          wcp  = (float*)(ws + 48 * MB);
  float*          attP = (float*)(ws + 48 * MB);
  unsigned short* a1   = (unsigned short*)(ws + 80 * MB);
  float*          ffP  = (float*)(ws + 48 * MB);

  const int nZ = kM * kD;  // 4194304

  // --- weight prep ---
  cast_transpose_kernel<<<dim3(kD / 32, kD / 32), dim3(32, 32), 0, stream>>>(
      Wo, WoT, kD, kD, (float)kS);                 // WoT[n][f] = 2048*Wo[f][n]
  cast_bf16_kernel<<<dim3(kD * kD / 1024), dim3(256), 0, stream>>>(Wv, WvBf, kD * kD);
  bias_gemv_part_kernel<<<dim3(128), dim3(256), 0, stream>>>(bv, Wo, bprt);
  bias_gemv_fin_kernel<<<dim3(4), dim3(256), 0, stream>>>(bprt, bo, bc);
  cast_bf16_kernel<<<dim3(nZ / 1024), dim3(256), 0, stream>>>(z, zbf, nZ);

  // WcT[m][n] = sum_f WoT[m][f]*WvBf[n][f], split-K x4 (grid 256), then
  // combine + identity + bf16.
  gemm_bt<0, 0><<<dim3(256), dim3(256), 0, stream>>>(
      WoT, WvBf, nullptr, wcp, kD, kD, kD, kD / 128, 64, 256, (size_t)kD * kD);
  combine_wc_kernel<<<dim3(1024), dim3(256), 0, stream>>>(wcp, WcT);

  // attP = z @ (I+Wc) + bc, split-K x2 (grid 512)
  gemm_bt<0, 0><<<dim3(512), dim3(256), 0, stream>>>(
      zbf, WcT, bc, attP, kM, kD, kD, kD / 128, 256, 512, (size_t)kM * kD);

  // h1 = LN(attP0 + attP1)
  ln_res_kernel<2><<<dim3(kM), dim3(256), 0, stream>>>(
      attP, attP + (size_t)kM * kD, nullptr, lng, lnb, h1f, h1bf);

  // FF1: a1 = relu(h1 @ W1 + b1), grid 1024, no split
  cast_transpose_kernel<<<dim3(kFF / 32, kD / 32), dim3(32, 32), 0, stream>>>(
      W1, wT, kD, kFF, 1.0f);
  gemm_bt<1, 1><<<dim3(1024), dim3(256), 0, stream>>>(
      h1bf, wT, b1, a1, kM, kFF, kD, kFF / 128, 1024, kD, 0);

  // FF2: ffP = a1 @ W2 + b2, split-K x2 (grid 512)
  cast_transpose_kernel<<<dim3(kD / 32, kFF / 32), dim3(32, 32), 0, stream>>>(
      W2, wT, kFF, kD, 1.0f);
  gemm_bt<0, 0><<<dim3(512), dim3(256), 0, stream>>>(
      a1, wT, b2, ffP, kM, kD, kFF, kD / 128, 256, kFF / 2, (size_t)kM * kD);

  // out = LN(h1 + ffP0 + ffP1)
  ln_res_kernel<3><<<dim3(kM), dim3(256), 0, stream>>>(
      h1f, ffP, ffP + (size_t)kM * kD, lng, lnb, out, nullptr);
}